// Round 5
// baseline (6859.019 us; speedup 1.0000x reference)
//
#include <hip/hip_runtime.h>
#include <math.h>

#define HH 256
#define FIN 6
#define TT 4096
#define BB 32
#define TH 0.05f

typedef _Float16 h2 __attribute__((ext_vector_type(2)));
typedef int iv32 __attribute__((ext_vector_type(32)));   // 32 VGPRs = 32 packed h2
struct H8 { h2 a, b, c, d; };   // 16 B = 8 halfs

__device__ __forceinline__ int packh2(float a, float b) {
    h2 v = { (_Float16)a, (_Float16)b };
    return __builtin_bit_cast(int, v);
}
__device__ __forceinline__ h2 toh2(int x) { return __builtin_bit_cast(h2, x); }

__device__ __forceinline__ float hswish(float v) {
    float c = fminf(fmaxf(v + 3.0f, 0.0f), 6.0f);
    return v * c * (1.0f / 6.0f);
}
__device__ __forceinline__ float fexp2(float x) { return __builtin_amdgcn_exp2f(x); }
__device__ __forceinline__ float frcp(float x)  { return __builtin_amdgcn_rcpf(x); }
__device__ __forceinline__ float sigm(float x)  { return frcp(1.0f + fexp2(-1.44269504f * x)); }
__device__ __forceinline__ float tanhf_fast(float x) {
    float ax = fabsf(x);
    float e = fexp2(2.88539008f * ax);           // exp(2|x|)
    float t = 1.0f - 2.0f * frcp(e + 1.0f);      // tanh(|x|)
    return copysignf(t, x);
}

// Kernel 1: feats (B,T,6) into ws, conv skip path into d_out.
__global__ __launch_bounds__(256) void k_prep(
        const float* __restrict__ x, const float* __restrict__ Wc1,
        const float* __restrict__ Wc2, float* __restrict__ feats,
        float* __restrict__ out) {
    int idx = blockIdx.x * 256 + threadIdx.x;   // b*T + t
    if (idx >= BB * TT) return;
    int b = idx >> 12;
    int t = idx & (TT - 1);
    const float* xb = x + (size_t)b * TT * 2;
    float i0 = xb[t * 2 + 0], q0 = xb[t * 2 + 1];
    float ip = (t > 0) ? xb[(t - 1) * 2 + 0] : 0.0f;
    float qp = (t > 0) ? xb[(t - 1) * 2 + 1] : 0.0f;
    float amp2 = i0 * i0 + q0 * q0;
    float amp  = sqrtf(fmaxf(amp2, 1e-12f));
    float amp3 = amp * amp2;
    float* f = feats + (size_t)idx * 6;
    f[0] = i0; f[1] = q0; f[2] = amp; f[3] = amp3; f[4] = ip; f[5] = qp;

    float c1[3];
#pragma unroll
    for (int m = 0; m < 3; m++) {
        float acc = 0.0f;
#pragma unroll
        for (int k = 0; k < 3; k++) {
            int tt = t + (k - 1) * 16;
            if (tt >= 0 && tt < TT) {
                acc += Wc1[m * 6 + 0 * 3 + k] * xb[tt * 2 + 0];
                acc += Wc1[m * 6 + 1 * 3 + k] * xb[tt * 2 + 1];
            }
        }
        c1[m] = hswish(acc);
    }
#pragma unroll
    for (int o = 0; o < 2; o++) {
        float acc = Wc2[o * 3 + 0] * c1[0] + Wc2[o * 3 + 1] * c1[1] + Wc2[o * 3 + 2] * c1[2];
        out[(size_t)idx * 2 + o] = hswish(acc);
    }
}

// Kernel 2: delta-GRU, one block (1 CU) per batch, 1024 threads (16 waves,
// 4 waves/SIMD -> the allocator's natural 128-VGPR operating point).
// 4-way K-split: lanes (l, l+16, l+32, l+48) co-own h-row wv*16+(l&15);
// each thread holds a K-QUARTER of all 3 gate rows as packed fp16
// (3 x 32 h2 = 96 VGPRs). Quarter q also owns fp32 mac_x slice for
// features {2q, 2q+1} (f>=6 padded 0), folded into the same accumulators.
// Partials combine via shfl_xor(16)+shfl_xor(32) -> identical full sums in
// all 4 lanes -> phase C stays thread-local. One barrier per step.
__global__ __attribute__((amdgpu_flat_work_group_size(1024, 1024), amdgpu_waves_per_eu(4, 4)))
void k_gru(
        const float* __restrict__ feats, const float* __restrict__ Wx,
        const float* __restrict__ Wh, const float* __restrict__ Wo,
        float* __restrict__ out) {
    __shared__ float s_out[TT * 2];                    // 32 KB output accumulator
    __shared__ __align__(16) _Float16 s_dhh[2][HH];    // 1 KB, double-buffered dh (fp16)
    __shared__ __align__(16) float s_dxf[2][8];        // dx fp32, padded to 8
    __shared__ float s_xp[8];                          // persistent x_p state
    __shared__ float s_feat[2][128 * FIN];             // 6 KB, double-buffered feat windows

    const int tid  = threadIdx.x;
    const int wv   = tid >> 6;                // wave 0..15
    const int lane = tid & 63;
    const int q    = lane >> 4;               // K-quarter 0..3
    const int sub  = lane & 15;
    const int row  = wv * 16 + sub;           // h-row 0..255
    const int b    = blockIdx.x;
    const float* fb = feats + (size_t)b * TT * FIN;

    for (int i = tid; i < TT * 2; i += 1024) s_out[i] = 0.0f;
    if (tid < 128 * FIN) s_feat[0][tid] = fb[tid];
    if (tid < 8) { s_xp[tid] = 0.0f; s_dxf[0][tid] = 0.0f; s_dxf[1][tid] = 0.0f; }

    // persistent weights: 3 gate-rows, this thread's K-quarter, packed fp16
    iv32 wrv{}, wzv{}, wnv{};
    {
        const int k0 = q * 64;
        const float4* p0 = (const float4*)(Wh + (size_t)(0 * HH + row) * HH + k0);
        const float4* p1 = (const float4*)(Wh + (size_t)(1 * HH + row) * HH + k0);
        const float4* p2 = (const float4*)(Wh + (size_t)(2 * HH + row) * HH + k0);
#pragma unroll
        for (int c = 0; c < 16; c++) {
            float4 v0 = p0[c], v1 = p1[c], v2 = p2[c];
            wrv[2 * c]     = packh2(v0.x, v0.y);
            wrv[2 * c + 1] = packh2(v0.z, v0.w);
            wzv[2 * c]     = packh2(v1.x, v1.y);
            wzv[2 * c + 1] = packh2(v1.z, v1.w);
            wnv[2 * c]     = packh2(v2.x, v2.y);
            wnv[2 * c + 1] = packh2(v2.z, v2.w);
        }
    }
    // fp32 Wx slice: features {2q, 2q+1}, zero-padded past FIN=6
    const int f0 = 2 * q, f1 = 2 * q + 1;
    const float wxr0 = (f0 < FIN) ? Wx[(size_t)(0 * HH + row) * FIN + f0] : 0.0f;
    const float wxr1 = (f1 < FIN) ? Wx[(size_t)(0 * HH + row) * FIN + f1] : 0.0f;
    const float wxz0 = (f0 < FIN) ? Wx[(size_t)(1 * HH + row) * FIN + f0] : 0.0f;
    const float wxz1 = (f1 < FIN) ? Wx[(size_t)(1 * HH + row) * FIN + f1] : 0.0f;
    const float wxn0 = (f0 < FIN) ? Wx[(size_t)(2 * HH + row) * FIN + f0] : 0.0f;
    const float wxn1 = (f1 < FIN) ? Wx[(size_t)(2 * HH + row) * FIN + f1] : 0.0f;
    const float woc  = (q == 0) ? Wo[row] : ((q == 1) ? Wo[HH + row] : 0.0f);

    float h = 0.0f, hp = 0.0f, dmr = 0.0f, dmz = 0.0f, dmn = 0.0f, dmnh = 0.0f;

    __syncthreads();

#pragma unroll 1
    for (int t = 0; t < TT; t++) {
        const int tb = t & 1;

        // stage NEXT feats window mid-way through the current one (WAR-safe)
        if ((t & 127) == 64 && t + 64 < TT) {
            const int w = (t >> 7) + 1;
            if (tid < 128 * FIN)
                s_feat[w & 1][tid] = fb[(size_t)w * 128 * FIN + tid];
        }

        // ---- phase A: thresholded deltas ----
        {
            float dh = h - hp;
            bool keep = fabsf(dh) >= TH;
            if (q == 0) s_dhh[tb][row] = (_Float16)(keep ? dh : 0.0f);
            if (keep) hp = h;
        }
        if (tid < FIN) {
            float fcur = s_feat[(t >> 7) & 1][(t & 127) * FIN + tid];
            float xp = s_xp[tid];
            float dxv = fcur - xp;
            bool keep = fabsf(dxv) >= TH;
            s_dxf[tb][tid] = keep ? dxv : 0.0f;
            if (keep) s_xp[tid] = fcur;
        }
        __syncthreads();

        // ---- phase B: quarter mac_x (fp32) + quarter fp16 dot ----
        float ar, az, anx, anh = 0.0f;
        {
            float dxa = s_dxf[tb][f0], dxb = s_dxf[tb][f1];
            ar  = dxa * wxr0; ar  = fmaf(dxb, wxr1, ar);
            az  = dxa * wxz0; az  = fmaf(dxb, wxz1, az);
            anx = dxa * wxn0; anx = fmaf(dxb, wxn1, anx);
        }
        {
            const H8* dp = (const H8*)(s_dhh[tb] + (q << 6));
#pragma unroll
            for (int c = 0; c < 8; c++) {
                H8 d = dp[c];
                ar  = __builtin_amdgcn_fdot2(d.a, toh2(wrv[4 * c + 0]), ar,  false);
                az  = __builtin_amdgcn_fdot2(d.a, toh2(wzv[4 * c + 0]), az,  false);
                anh = __builtin_amdgcn_fdot2(d.a, toh2(wnv[4 * c + 0]), anh, false);
                ar  = __builtin_amdgcn_fdot2(d.b, toh2(wrv[4 * c + 1]), ar,  false);
                az  = __builtin_amdgcn_fdot2(d.b, toh2(wzv[4 * c + 1]), az,  false);
                anh = __builtin_amdgcn_fdot2(d.b, toh2(wnv[4 * c + 1]), anh, false);
                ar  = __builtin_amdgcn_fdot2(d.c, toh2(wrv[4 * c + 2]), ar,  false);
                az  = __builtin_amdgcn_fdot2(d.c, toh2(wzv[4 * c + 2]), az,  false);
                anh = __builtin_amdgcn_fdot2(d.c, toh2(wnv[4 * c + 2]), anh, false);
                ar  = __builtin_amdgcn_fdot2(d.d, toh2(wrv[4 * c + 3]), ar,  false);
                az  = __builtin_amdgcn_fdot2(d.d, toh2(wzv[4 * c + 3]), az,  false);
                anh = __builtin_amdgcn_fdot2(d.d, toh2(wnv[4 * c + 3]), anh, false);
            }
        }
        // combine quarters: identical full sums land in all 4 lanes
        ar  += __shfl_xor(ar, 16, 64);  ar  += __shfl_xor(ar, 32, 64);
        az  += __shfl_xor(az, 16, 64);  az  += __shfl_xor(az, 32, 64);
        anx += __shfl_xor(anx, 16, 64); anx += __shfl_xor(anx, 32, 64);
        anh += __shfl_xor(anh, 16, 64); anh += __shfl_xor(anh, 32, 64);

        dmr  += ar;      // dm_r = dm_r_old + mac_x_r + mac_h_r
        dmz  += az;
        dmn  += anx;     // dm_n = dm_n_old + mac_x_n
        dmnh += anh;     // dm_nh += mac_h_n

        // ---- phase C (thread-local, redundant in all quarters) ----
        {
            float r = sigm(dmr);
            float z = sigm(dmz);
            float nn = tanhf_fast(dmn + r * dmnh);
            h = (1.0f - z) * nn + z * h;
        }

        // ---- output: quarter 0 -> ch0, quarter 1 -> ch1 ----
        {
            float p = h * woc;
            p += __shfl_xor(p, 1, 64);
            p += __shfl_xor(p, 2, 64);
            p += __shfl_xor(p, 4, 64);
            p += __shfl_xor(p, 8, 64);
            if (sub == 0 && q < 2) atomicAdd(&s_out[2 * t + q], p);
        }
    }

    __syncthreads();
    const size_t outbase = (size_t)b * TT * 2;
    for (int i = tid; i < TT * 2; i += 1024) out[outbase + i] += s_out[i];
}

extern "C" void kernel_launch(void* const* d_in, const int* in_sizes, int n_in,
                              void* d_out, int out_size, void* d_ws, size_t ws_size,
                              hipStream_t stream) {
    const float* x   = (const float*)d_in[0];
    const float* Wx  = (const float*)d_in[1];
    const float* Wh  = (const float*)d_in[2];
    const float* Wo  = (const float*)d_in[3];
    const float* Wc1 = (const float*)d_in[4];
    const float* Wc2 = (const float*)d_in[5];
    float* out = (float*)d_out;
    float* feats = (float*)d_ws;              // B*T*6 fp32 = 3.1 MB

    k_prep<<<(BB * TT + 255) / 256, 256, 0, stream>>>(x, Wc1, Wc2, feats, out);
    k_gru<<<BB, 1024, 0, stream>>>(feats, Wx, Wh, Wo, out);
}